// Round 8
// baseline (206.969 us; speedup 1.0000x reference)
//
#include <hip/hip_runtime.h>

// KnowledgeConsistentAttention v7b (MI355X / gfx950)
// sumpool3x3(scores)[p,q] = kern[p,:] . G[:,q], G = sumpool3x3(fg)
// => flash attention, K=V=kern (normalized fg cols + eps), Q = G cols, d=64.
//
// v7b: fixes v7's reduce bug (l1 offset was 65536 = BYTE size of the h-stride;
// correct float offset is 16384) and pins launch_bounds(1024,8) so 2 blocks/CU
// (8 waves/SIMD) is guaranteed (VGPR=64, LDS ~72KB x2 <= 160KB).

typedef __bf16 bf16_t;
typedef __bf16 bf16x2 __attribute__((ext_vector_type(2)));
typedef __bf16 bf16x8 __attribute__((ext_vector_type(8)));
typedef float f32x4 __attribute__((ext_vector_type(4)));

#define HW_ 4096
#define CH 64

static __device__ __forceinline__ void gload_lds16(const void* gsrc, void* lds_dst) {
  __builtin_amdgcn_global_load_lds(
      (const __attribute__((address_space(1))) unsigned int*)gsrc,
      (__attribute__((address_space(3))) unsigned int*)lds_dst, 16, 0, 0);
}

static __device__ __forceinline__ int pack_bf16x2(float a, float b) {
  bf16x2 p; p[0] = (bf16_t)a; p[1] = (bf16_t)b;
  return __builtin_bit_cast(int, p);
}

// ---------------- prep: kern (2 layouts) + pooled/prescaled Q ----------------
__global__ __launch_bounds__(1024, 1) void kca_prep(const float* __restrict__ fg,
                                                    char* __restrict__ KpB,
                                                    char* __restrict__ KBB,
                                                    char* __restrict__ GtB) {
  const int b = blockIdx.x >> 6, y = blockIdx.x & 63;
  const int t = threadIdx.x;
  const float* F = fg + (size_t)b * (CH * HW_);

  __shared__ float  Ft[3 * 64 * 64];   // [r][c][x] f32, rows y-1..y+1
  __shared__ bf16_t Ks[64 * 72];       // [x][c], stride 72 (144B, 16B-aligned)
  __shared__ bf16_t Gs[64 * 72];
  __shared__ float  red[16][64];
  __shared__ float  rn[64];

#pragma unroll
  for (int k = 0; k < 3; ++k) {
    const int o = t + k * 1024;          // f32x4 index
    const int r = o >> 10, c = (o >> 4) & 63, x4 = o & 15;
    const int gy = y - 1 + r;
    f32x4 v = {0.f, 0.f, 0.f, 0.f};
    if (gy >= 0 && gy <= 63) v = *(const f32x4*)(F + c * HW_ + gy * 64 + x4 * 4);
    *(f32x4*)&Ft[o * 4] = v;
  }
  __syncthreads();

  const int x = t & 63, c0 = t >> 6;     // c0 in 0..15 -> channels 4*c0..+3
  float v4[4], g4[4], ssq = 0.f;
#pragma unroll
  for (int i = 0; i < 4; ++i) {
    const int c = c0 * 4 + i;
    const float v = Ft[4096 + c * 64 + x] + 1e-7f;
    v4[i] = v; ssq = fmaf(v, v, ssq);
    float s = 0.f;
#pragma unroll
    for (int r = 0; r < 3; ++r) {
      const float* row = &Ft[r * 4096 + c * 64];
      float vv = row[x];
      if (x > 0)  vv += row[x - 1];
      if (x < 63) vv += row[x + 1];
      s += vv;
    }
    g4[i] = s * 1.4426950408889634f;     // log2e prescale (exp2-domain softmax)
  }
  red[c0][x] = ssq;
  __syncthreads();
  if (t < 512) red[t >> 6][t & 63] += red[(t >> 6) + 8][t & 63];
  __syncthreads();
  if (t < 256) red[t >> 6][t & 63] += red[(t >> 6) + 4][t & 63];
  __syncthreads();
  if (t < 64) rn[t] = 1.0f / sqrtf(red[0][t] + red[1][t] + red[2][t] + red[3][t]);
  __syncthreads();
  {
    const float rv = rn[x];
    bf16x2* ksp = (bf16x2*)((char*)Ks + x * 144 + c0 * 8);
    bf16x2* gsp = (bf16x2*)((char*)Gs + x * 144 + c0 * 8);
    bf16x2 k0; k0[0] = (bf16_t)(v4[0] * rv); k0[1] = (bf16_t)(v4[1] * rv);
    bf16x2 k1; k1[0] = (bf16_t)(v4[2] * rv); k1[1] = (bf16_t)(v4[3] * rv);
    bf16x2 g0; g0[0] = (bf16_t)g4[0]; g0[1] = (bf16_t)g4[1];
    bf16x2 g1; g1[0] = (bf16_t)g4[2]; g1[1] = (bf16_t)g4[3];
    ksp[0] = k0; ksp[1] = k1;
    gsp[0] = g0; gsp[1] = g1;
  }
  __syncthreads();

  char* Kp_b = KpB + (size_t)b * (HW_ * CH * 2) + (size_t)y * 8192;  // [p][c] 128B rows
  char* Gt_b = GtB + (size_t)b * (HW_ * CH * 2) + (size_t)y * 8192;  // [q][c] 128B rows
  char* KB_b = KBB + (size_t)b * (HW_ * CH * 2);                     // [tile][mt][lane][16B]
  if (t < 512) {
    const int row = t >> 3, colb = (t & 7) * 16;
    *(bf16x8*)(Kp_b + row * 128 + colb) = *(const bf16x8*)((char*)Ks + row * 144 + colb);
    // KB: GEMM2 B-fragment order with slot permutation baked in.
    // lane(l15,lg) word j = kern[tile*32 + 16*(j>>2) + 4*lg + (j&3)][16*mt + l15]
    const int tile = t >> 8;           // 0..1
    const int mt   = (t >> 6) & 3;
    const int ln   = t & 63;
    const int l15_ = ln & 15, lg_ = ln >> 4;
    bf16x8 kv;
#pragma unroll
    for (int j = 0; j < 8; ++j) {
      const int pl = tile * 32 + 16 * (j >> 2) + 4 * lg_ + (j & 3);
      kv[j] = Ks[pl * 72 + 16 * mt + l15_];
    }
    *(bf16x8*)(KB_b + (size_t)(2 * y + tile) * 4096 + mt * 1024 + ln * 16) = kv;
  } else {
    const int s = t - 512;
    const int row = s >> 3, colb = (s & 7) * 16;
    *(bf16x8*)(Gt_b + row * 128 + colb) = *(const bf16x8*)((char*)Gs + row * 144 + colb);
  }
}

// ---------------- main: fused flash attention (half the keys per block) ----------------
__global__ __launch_bounds__(1024, 8) void kca_attn(const char* __restrict__ KpB,
                                                    const char* __restrict__ KBB,
                                                    const char* __restrict__ GtB,
                                                    float* __restrict__ out,
                                                    float* __restrict__ po1,
                                                    float* __restrict__ lw) {
  // XCD-aware remap over 512 blocks: each XCD owns one (half, batch) slice
  const int sw_id = ((blockIdx.x & 7) << 6) | (blockIdx.x >> 3);
  const int h = sw_id >> 8;            // key half 0..1
  const int b = (sw_id >> 6) & 3, y = sw_id & 63;
  const int t = threadIdx.x;
  const int lane = t & 63, w = t >> 6;
  const int g = w & 7;           // p-group 0..7 (keys h*2048 + g*256 .. +256)
  const int st = w >> 3;         // q-strip 0..1 (q offset st*32)
  const int l15 = lane & 15, lg = lane >> 4;

  const char* Kp_b = KpB + (size_t)b * (HW_ * CH * 2);
  const char* KB_b = KBB + (size_t)b * (HW_ * CH * 2);
  const char* Gt_b = GtB + (size_t)b * (HW_ * CH * 2);
  float* dstO = (h ? po1 : out) + (size_t)b * (CH * HW_);

  __shared__ __align__(16) char SM[69632];   // loop: Kp 8g x 2buf x 4K; combine: 4 x [64][68] f32
  __shared__ float mll[8][64];

  char* KpG = SM + g * 8192;

  // Q fragments (wave's 32 queries, pre-scaled by log2e)
  bf16x8 qb00, qb01, qb10, qb11;
  {
    const char* qr0 = Gt_b + (size_t)(y * 64 + st * 32 + l15) * 128;
    const char* qr1 = qr0 + 16 * 128;
    qb00 = *(const bf16x8*)(qr0 + 16 * lg);
    qb01 = *(const bf16x8*)(qr0 + 64 + 16 * lg);
    qb10 = *(const bf16x8*)(qr1 + 16 * lg);
    qb11 = *(const bf16x8*)(qr1 + 64 + 16 * lg);
  }

  // staging constants (group Kp tile = 256 x 16B chunks, 2 waves x 2 chunks)
  const int cA = st * 128 + lane, cB = cA + 64;
  const int rA1 = cA >> 3, rB1 = cB >> 3;
  const size_t kpoffA = (size_t)rA1 * 128 + (((cA & 7) * 16) ^ ((rA1 & 7) << 4));
  const size_t kpoffB = (size_t)rB1 * 128 + (((cB & 7) * 16) ^ ((rB1 & 7) << 4));

#define STAGE_KP(D, P0)                                                          \
  do {                                                                           \
    gload_lds16(Kp_b + (size_t)(P0) * 128 + kpoffA, KpG + (D) * 4096 + cA * 16); \
    gload_lds16(Kp_b + (size_t)(P0) * 128 + kpoffB, KpG + (D) * 4096 + cB * 16); \
  } while (0)

  f32x4 oaccT[2][4];
#pragma unroll
  for (int s = 0; s < 2; ++s)
#pragma unroll
    for (int mt = 0; mt < 4; ++mt) { oaccT[s][mt][0]=0.f; oaccT[s][mt][1]=0.f; oaccT[s][mt][2]=0.f; oaccT[s][mt][3]=0.f; }
  float lpart0 = 0.f, lpart1 = 0.f;

  const int pb0 = h * 2048 + g * 256;
  STAGE_KP(0, pb0);
  int cur = 0;
  for (int it = 0; it < 8; ++it) {
    __syncthreads();                       // Kp[cur] staged
    // B-fragments for this tile: 4 coalesced 1KB wave-loads, L1/L2-resident
    const char* kbp = KB_b + (size_t)((pb0 >> 5) + it) * 4096 + lane * 16;
    const bf16x8 kb0 = *(const bf16x8*)(kbp);
    const bf16x8 kb1 = *(const bf16x8*)(kbp + 1024);
    const bf16x8 kb2 = *(const bf16x8*)(kbp + 2048);
    const bf16x8 kb3 = *(const bf16x8*)(kbp + 3072);
    if (it + 1 < 8) STAGE_KP(cur ^ 1, pb0 + (it + 1) * 32);

    // ---- GEMM1: S[s][p = f*16+4lg+r][q = st*32+s*16+l15], K=64 channels ----
    const char* kp = KpG + cur * 4096;
    f32x4 S[2][2];
#pragma unroll
    for (int f = 0; f < 2; ++f) {
      const int r = f * 16 + l15, swr = (r & 7) << 4;
      bf16x8 a0 = *(const bf16x8*)(kp + r * 128 + ((16 * lg) ^ swr));
      bf16x8 a1 = *(const bf16x8*)(kp + r * 128 + ((64 + 16 * lg) ^ swr));
      f32x4 z0 = {0.f, 0.f, 0.f, 0.f};
      z0 = __builtin_amdgcn_mfma_f32_16x16x32_bf16(a0, qb00, z0, 0, 0, 0);
      z0 = __builtin_amdgcn_mfma_f32_16x16x32_bf16(a1, qb01, z0, 0, 0, 0);
      S[0][f] = z0;
      f32x4 z1 = {0.f, 0.f, 0.f, 0.f};
      z1 = __builtin_amdgcn_mfma_f32_16x16x32_bf16(a0, qb10, z1, 0, 0, 0);
      z1 = __builtin_amdgcn_mfma_f32_16x16x32_bf16(a1, qb11, z1, 0, 0, 0);
      S[1][f] = z1;
    }

    // ---- fixed-bias softmax numerators: P = exp2(S) (no max needed) ----
    union { int wd[4]; bf16x8 v; } pa0, pa1;
    {
      const float e0 = exp2f(S[0][0][0]), e1 = exp2f(S[0][0][1]);
      const float e2 = exp2f(S[0][0][2]), e3 = exp2f(S[0][0][3]);
      const float e4 = exp2f(S[0][1][0]), e5 = exp2f(S[0][1][1]);
      const float e6 = exp2f(S[0][1][2]), e7 = exp2f(S[0][1][3]);
      lpart0 += ((e0 + e1) + (e2 + e3)) + ((e4 + e5) + (e6 + e7));
      pa0.wd[0] = pack_bf16x2(e0, e1); pa0.wd[1] = pack_bf16x2(e2, e3);
      pa0.wd[2] = pack_bf16x2(e4, e5); pa0.wd[3] = pack_bf16x2(e6, e7);
    }
    {
      const float e0 = exp2f(S[1][0][0]), e1 = exp2f(S[1][0][1]);
      const float e2 = exp2f(S[1][0][2]), e3 = exp2f(S[1][0][3]);
      const float e4 = exp2f(S[1][1][0]), e5 = exp2f(S[1][1][1]);
      const float e6 = exp2f(S[1][1][2]), e7 = exp2f(S[1][1][3]);
      lpart1 += ((e0 + e1) + (e2 + e3)) + ((e4 + e5) + (e6 + e7));
      pa1.wd[0] = pack_bf16x2(e0, e1); pa1.wd[1] = pack_bf16x2(e2, e3);
      pa1.wd[2] = pack_bf16x2(e4, e5); pa1.wd[3] = pack_bf16x2(e6, e7);
    }

    // ---- GEMM2 (swapped): O^T[q = 4lg+r][c = 16mt+l15] += P . kern ----
    oaccT[0][0] = __builtin_amdgcn_mfma_f32_16x16x32_bf16(pa0.v, kb0, oaccT[0][0], 0, 0, 0);
    oaccT[1][0] = __builtin_amdgcn_mfma_f32_16x16x32_bf16(pa1.v, kb0, oaccT[1][0], 0, 0, 0);
    oaccT[0][1] = __builtin_amdgcn_mfma_f32_16x16x32_bf16(pa0.v, kb1, oaccT[0][1], 0, 0, 0);
    oaccT[1][1] = __builtin_amdgcn_mfma_f32_16x16x32_bf16(pa1.v, kb1, oaccT[1][1], 0, 0, 0);
    oaccT[0][2] = __builtin_amdgcn_mfma_f32_16x16x32_bf16(pa0.v, kb2, oaccT[0][2], 0, 0, 0);
    oaccT[1][2] = __builtin_amdgcn_mfma_f32_16x16x32_bf16(pa1.v, kb2, oaccT[1][2], 0, 0, 0);
    oaccT[0][3] = __builtin_amdgcn_mfma_f32_16x16x32_bf16(pa0.v, kb3, oaccT[0][3], 0, 0, 0);
    oaccT[1][3] = __builtin_amdgcn_mfma_f32_16x16x32_bf16(pa1.v, kb3, oaccT[1][3], 0, 0, 0);
    cur ^= 1;
  }
#undef STAGE_KP

  // ---- reduce l partials over lane-groups, publish per p-group ----
  lpart0 += __shfl_xor(lpart0, 16); lpart0 += __shfl_xor(lpart0, 32);
  lpart1 += __shfl_xor(lpart1, 16); lpart1 += __shfl_xor(lpart1, 32);
  if (lg == 0) {
    mll[g][st * 32 + l15]      = lpart0;
    mll[g][st * 32 + 16 + l15] = lpart1;
  }
  __syncthreads();                                   // C1: loop LDS dead
  if (t < 64) {
    float L = 0.f;
#pragma unroll
    for (int k = 0; k < 8; ++k) L += mll[k][t];
    lw[(size_t)((h * 4 + b) * 64 + y) * 64 + t] = L;   // raw half-l
  }
  // combine O^T partials: 4 regions [c=64][q stride 68] f32 on dead staging LDS
  float* Rg = (float*)SM + (g >> 1) * 4352;
  if ((g & 1) == 0) {
#pragma unroll
    for (int s = 0; s < 2; ++s)
#pragma unroll
      for (int mt = 0; mt < 4; ++mt)
#pragma unroll
        for (int r = 0; r < 4; ++r)
          Rg[(16 * mt + l15) * 68 + st * 32 + s * 16 + 4 * lg + r] = oaccT[s][mt][r];
  }
  __syncthreads();                                   // C2
  if (g & 1) {
#pragma unroll
    for (int s = 0; s < 2; ++s)
#pragma unroll
      for (int mt = 0; mt < 4; ++mt)
#pragma unroll
        for (int r = 0; r < 4; ++r)
          Rg[(16 * mt + l15) * 68 + st * 32 + s * 16 + 4 * lg + r] += oaccT[s][mt][r];
  }
  __syncthreads();                                   // C3
  {
    const int c = t >> 4, q4 = (t & 15) * 4;
    const float* R0 = (const float*)SM;
    f32x4 v = *(const f32x4*)(R0 + c * 68 + q4);
    v += *(const f32x4*)(R0 + 4352 + c * 68 + q4);
    v += *(const f32x4*)(R0 + 8704 + c * 68 + q4);
    v += *(const f32x4*)(R0 + 13056 + c * 68 + q4);
    *(f32x4*)(dstO + (size_t)c * HW_ + y * 64 + q4) = v;   // raw partial sums
  }
}

// ---------------- reduce: out = (P0 + P1) / (l0 + l1), in place ----------------
__global__ __launch_bounds__(256, 8) void kca_reduce(float* __restrict__ out,
                                                     const float* __restrict__ po1,
                                                     const float* __restrict__ lw) {
  const size_t idx = ((size_t)blockIdx.x * 256 + threadIdx.x) * 4;  // element idx, q%4==0
  const int b = (int)(idx >> 18);
  const int y = (int)((idx >> 6) & 63);
  const int q = (int)(idx & 63);
  const size_t lidx = (size_t)(b * 64 + y) * 64 + q;
  const f32x4 a  = *(const f32x4*)(out + idx);
  const f32x4 p  = *(const f32x4*)(po1 + idx);
  const f32x4 l0 = *(const f32x4*)(lw + lidx);
  const f32x4 l1 = *(const f32x4*)(lw + 16384 + lidx);   // h-stride = 4*64*64 FLOATS
  f32x4 o;
#pragma unroll
  for (int j = 0; j < 4; ++j) o[j] = (a[j] + p[j]) * (1.0f / (l0[j] + l1[j]));
  *(f32x4*)(out + idx) = o;
}

extern "C" void kernel_launch(void* const* d_in, const int* in_sizes, int n_in,
                              void* d_out, int out_size, void* d_ws, size_t ws_size,
                              hipStream_t stream) {
  const float* fg = (const float*)d_in[0];
  float* out = (float*)d_out;
  char* ws = (char*)d_ws;
  char* Kp  = ws;                    // 2 MB  [b][p][c] bf16 (A-side kern)
  char* KB  = ws + (2u << 20);       // 2 MB  [b][tile][mt][lane][16B] (B-side kern)
  char* Gt  = ws + (4u << 20);       // 2 MB  [b][q][c] bf16 (pooled Q, log2e-scaled)
  float* PO1 = (float*)(ws + (6u << 20));   // 4 MB  half-1 partial O, out layout
  float* LW  = (float*)(ws + (10u << 20));  // 512 KB [h][b][y][64] l sums
  hipLaunchKernelGGL(kca_prep, dim3(256), dim3(1024), 0, stream, fg, Kp, KB, Gt);
  hipLaunchKernelGGL(kca_attn, dim3(512), dim3(1024), 0, stream, Kp, KB, Gt, out, PO1, LW);
  hipLaunchKernelGGL(kca_reduce, dim3(1024), dim3(256), 0, stream, out, PO1, LW);
}

// Round 9
// 54.360 us; speedup vs baseline: 3.8074x; 3.8074x over previous
//
#include <hip/hip_runtime.h>

// KnowledgeConsistentAttention v8 (MI355X / gfx950)
// sumpool3x3(scores)[p,q] = kern[p,:] . G[:,q], G = sumpool3x3(fg)
// => flash attention, K=V=kern (normalized fg cols + eps), Q = G cols, d=64.
//
// v8: = v7b but launch_bounds(1024,4) on attn. Round 8 showed (1024,8)
// over-constrains the allocator (VGPR 64->32, ~1GB scratch traffic/dispatch).
// With 64 VGPR + 70KB LDS the HW still co-schedules 2 blocks/CU on its own.

typedef __bf16 bf16_t;
typedef __bf16 bf16x2 __attribute__((ext_vector_type(2)));
typedef __bf16 bf16x8 __attribute__((ext_vector_type(8)));
typedef float f32x4 __attribute__((ext_vector_type(4)));

#define HW_ 4096
#define CH 64

static __device__ __forceinline__ void gload_lds16(const void* gsrc, void* lds_dst) {
  __builtin_amdgcn_global_load_lds(
      (const __attribute__((address_space(1))) unsigned int*)gsrc,
      (__attribute__((address_space(3))) unsigned int*)lds_dst, 16, 0, 0);
}

static __device__ __forceinline__ int pack_bf16x2(float a, float b) {
  bf16x2 p; p[0] = (bf16_t)a; p[1] = (bf16_t)b;
  return __builtin_bit_cast(int, p);
}

// ---------------- prep: kern (2 layouts) + pooled/prescaled Q ----------------
__global__ __launch_bounds__(1024, 1) void kca_prep(const float* __restrict__ fg,
                                                    char* __restrict__ KpB,
                                                    char* __restrict__ KBB,
                                                    char* __restrict__ GtB) {
  const int b = blockIdx.x >> 6, y = blockIdx.x & 63;
  const int t = threadIdx.x;
  const float* F = fg + (size_t)b * (CH * HW_);

  __shared__ float  Ft[3 * 64 * 64];   // [r][c][x] f32, rows y-1..y+1
  __shared__ bf16_t Ks[64 * 72];       // [x][c], stride 72 (144B, 16B-aligned)
  __shared__ bf16_t Gs[64 * 72];
  __shared__ float  red[16][64];
  __shared__ float  rn[64];

#pragma unroll
  for (int k = 0; k < 3; ++k) {
    const int o = t + k * 1024;          // f32x4 index
    const int r = o >> 10, c = (o >> 4) & 63, x4 = o & 15;
    const int gy = y - 1 + r;
    f32x4 v = {0.f, 0.f, 0.f, 0.f};
    if (gy >= 0 && gy <= 63) v = *(const f32x4*)(F + c * HW_ + gy * 64 + x4 * 4);
    *(f32x4*)&Ft[o * 4] = v;
  }
  __syncthreads();

  const int x = t & 63, c0 = t >> 6;     // c0 in 0..15 -> channels 4*c0..+3
  float v4[4], g4[4], ssq = 0.f;
#pragma unroll
  for (int i = 0; i < 4; ++i) {
    const int c = c0 * 4 + i;
    const float v = Ft[4096 + c * 64 + x] + 1e-7f;
    v4[i] = v; ssq = fmaf(v, v, ssq);
    float s = 0.f;
#pragma unroll
    for (int r = 0; r < 3; ++r) {
      const float* row = &Ft[r * 4096 + c * 64];
      float vv = row[x];
      if (x > 0)  vv += row[x - 1];
      if (x < 63) vv += row[x + 1];
      s += vv;
    }
    g4[i] = s * 1.4426950408889634f;     // log2e prescale (exp2-domain softmax)
  }
  red[c0][x] = ssq;
  __syncthreads();
  if (t < 512) red[t >> 6][t & 63] += red[(t >> 6) + 8][t & 63];
  __syncthreads();
  if (t < 256) red[t >> 6][t & 63] += red[(t >> 6) + 4][t & 63];
  __syncthreads();
  if (t < 64) rn[t] = 1.0f / sqrtf(red[0][t] + red[1][t] + red[2][t] + red[3][t]);
  __syncthreads();
  {
    const float rv = rn[x];
    bf16x2* ksp = (bf16x2*)((char*)Ks + x * 144 + c0 * 8);
    bf16x2* gsp = (bf16x2*)((char*)Gs + x * 144 + c0 * 8);
    bf16x2 k0; k0[0] = (bf16_t)(v4[0] * rv); k0[1] = (bf16_t)(v4[1] * rv);
    bf16x2 k1; k1[0] = (bf16_t)(v4[2] * rv); k1[1] = (bf16_t)(v4[3] * rv);
    bf16x2 g0; g0[0] = (bf16_t)g4[0]; g0[1] = (bf16_t)g4[1];
    bf16x2 g1; g1[0] = (bf16_t)g4[2]; g1[1] = (bf16_t)g4[3];
    ksp[0] = k0; ksp[1] = k1;
    gsp[0] = g0; gsp[1] = g1;
  }
  __syncthreads();

  char* Kp_b = KpB + (size_t)b * (HW_ * CH * 2) + (size_t)y * 8192;  // [p][c] 128B rows
  char* Gt_b = GtB + (size_t)b * (HW_ * CH * 2) + (size_t)y * 8192;  // [q][c] 128B rows
  char* KB_b = KBB + (size_t)b * (HW_ * CH * 2);                     // [tile][mt][lane][16B]
  if (t < 512) {
    const int row = t >> 3, colb = (t & 7) * 16;
    *(bf16x8*)(Kp_b + row * 128 + colb) = *(const bf16x8*)((char*)Ks + row * 144 + colb);
    // KB: GEMM2 B-fragment order with slot permutation baked in.
    // lane(l15,lg) word j = kern[tile*32 + 16*(j>>2) + 4*lg + (j&3)][16*mt + l15]
    const int tile = t >> 8;           // 0..1
    const int mt   = (t >> 6) & 3;
    const int ln   = t & 63;
    const int l15_ = ln & 15, lg_ = ln >> 4;
    bf16x8 kv;
#pragma unroll
    for (int j = 0; j < 8; ++j) {
      const int pl = tile * 32 + 16 * (j >> 2) + 4 * lg_ + (j & 3);
      kv[j] = Ks[pl * 72 + 16 * mt + l15_];
    }
    *(bf16x8*)(KB_b + (size_t)(2 * y + tile) * 4096 + mt * 1024 + ln * 16) = kv;
  } else {
    const int s = t - 512;
    const int row = s >> 3, colb = (s & 7) * 16;
    *(bf16x8*)(Gt_b + row * 128 + colb) = *(const bf16x8*)((char*)Gs + row * 144 + colb);
  }
}

// ---------------- main: fused flash attention (half the keys per block) ----------------
__global__ __launch_bounds__(1024, 4) void kca_attn(const char* __restrict__ KpB,
                                                    const char* __restrict__ KBB,
                                                    const char* __restrict__ GtB,
                                                    float* __restrict__ out,
                                                    float* __restrict__ po1,
                                                    float* __restrict__ lw) {
  // XCD-aware remap over 512 blocks: each XCD owns one (half, batch) slice
  const int sw_id = ((blockIdx.x & 7) << 6) | (blockIdx.x >> 3);
  const int h = sw_id >> 8;            // key half 0..1
  const int b = (sw_id >> 6) & 3, y = sw_id & 63;
  const int t = threadIdx.x;
  const int lane = t & 63, w = t >> 6;
  const int g = w & 7;           // p-group 0..7 (keys h*2048 + g*256 .. +256)
  const int st = w >> 3;         // q-strip 0..1 (q offset st*32)
  const int l15 = lane & 15, lg = lane >> 4;

  const char* Kp_b = KpB + (size_t)b * (HW_ * CH * 2);
  const char* KB_b = KBB + (size_t)b * (HW_ * CH * 2);
  const char* Gt_b = GtB + (size_t)b * (HW_ * CH * 2);
  float* dstO = (h ? po1 : out) + (size_t)b * (CH * HW_);

  __shared__ __align__(16) char SM[69632];   // loop: Kp 8g x 2buf x 4K; combine: 4 x [64][68] f32
  __shared__ float mll[8][64];

  char* KpG = SM + g * 8192;

  // Q fragments (wave's 32 queries, pre-scaled by log2e)
  bf16x8 qb00, qb01, qb10, qb11;
  {
    const char* qr0 = Gt_b + (size_t)(y * 64 + st * 32 + l15) * 128;
    const char* qr1 = qr0 + 16 * 128;
    qb00 = *(const bf16x8*)(qr0 + 16 * lg);
    qb01 = *(const bf16x8*)(qr0 + 64 + 16 * lg);
    qb10 = *(const bf16x8*)(qr1 + 16 * lg);
    qb11 = *(const bf16x8*)(qr1 + 64 + 16 * lg);
  }

  // staging constants (group Kp tile = 256 x 16B chunks, 2 waves x 2 chunks)
  const int cA = st * 128 + lane, cB = cA + 64;
  const int rA1 = cA >> 3, rB1 = cB >> 3;
  const size_t kpoffA = (size_t)rA1 * 128 + (((cA & 7) * 16) ^ ((rA1 & 7) << 4));
  const size_t kpoffB = (size_t)rB1 * 128 + (((cB & 7) * 16) ^ ((rB1 & 7) << 4));

#define STAGE_KP(D, P0)                                                          \
  do {                                                                           \
    gload_lds16(Kp_b + (size_t)(P0) * 128 + kpoffA, KpG + (D) * 4096 + cA * 16); \
    gload_lds16(Kp_b + (size_t)(P0) * 128 + kpoffB, KpG + (D) * 4096 + cB * 16); \
  } while (0)

  f32x4 oaccT[2][4];
#pragma unroll
  for (int s = 0; s < 2; ++s)
#pragma unroll
    for (int mt = 0; mt < 4; ++mt) { oaccT[s][mt][0]=0.f; oaccT[s][mt][1]=0.f; oaccT[s][mt][2]=0.f; oaccT[s][mt][3]=0.f; }
  float lpart0 = 0.f, lpart1 = 0.f;

  const int pb0 = h * 2048 + g * 256;
  STAGE_KP(0, pb0);
  int cur = 0;
  for (int it = 0; it < 8; ++it) {
    __syncthreads();                       // Kp[cur] staged
    // B-fragments for this tile: 4 coalesced 1KB wave-loads, L1/L2-resident
    const char* kbp = KB_b + (size_t)((pb0 >> 5) + it) * 4096 + lane * 16;
    const bf16x8 kb0 = *(const bf16x8*)(kbp);
    const bf16x8 kb1 = *(const bf16x8*)(kbp + 1024);
    const bf16x8 kb2 = *(const bf16x8*)(kbp + 2048);
    const bf16x8 kb3 = *(const bf16x8*)(kbp + 3072);
    if (it + 1 < 8) STAGE_KP(cur ^ 1, pb0 + (it + 1) * 32);

    // ---- GEMM1: S[s][p = f*16+4lg+r][q = st*32+s*16+l15], K=64 channels ----
    const char* kp = KpG + cur * 4096;
    f32x4 S[2][2];
#pragma unroll
    for (int f = 0; f < 2; ++f) {
      const int r = f * 16 + l15, swr = (r & 7) << 4;
      bf16x8 a0 = *(const bf16x8*)(kp + r * 128 + ((16 * lg) ^ swr));
      bf16x8 a1 = *(const bf16x8*)(kp + r * 128 + ((64 + 16 * lg) ^ swr));
      f32x4 z0 = {0.f, 0.f, 0.f, 0.f};
      z0 = __builtin_amdgcn_mfma_f32_16x16x32_bf16(a0, qb00, z0, 0, 0, 0);
      z0 = __builtin_amdgcn_mfma_f32_16x16x32_bf16(a1, qb01, z0, 0, 0, 0);
      S[0][f] = z0;
      f32x4 z1 = {0.f, 0.f, 0.f, 0.f};
      z1 = __builtin_amdgcn_mfma_f32_16x16x32_bf16(a0, qb10, z1, 0, 0, 0);
      z1 = __builtin_amdgcn_mfma_f32_16x16x32_bf16(a1, qb11, z1, 0, 0, 0);
      S[1][f] = z1;
    }

    // ---- fixed-bias softmax numerators: P = exp2(S) (no max needed) ----
    union { int wd[4]; bf16x8 v; } pa0, pa1;
    {
      const float e0 = exp2f(S[0][0][0]), e1 = exp2f(S[0][0][1]);
      const float e2 = exp2f(S[0][0][2]), e3 = exp2f(S[0][0][3]);
      const float e4 = exp2f(S[0][1][0]), e5 = exp2f(S[0][1][1]);
      const float e6 = exp2f(S[0][1][2]), e7 = exp2f(S[0][1][3]);
      lpart0 += ((e0 + e1) + (e2 + e3)) + ((e4 + e5) + (e6 + e7));
      pa0.wd[0] = pack_bf16x2(e0, e1); pa0.wd[1] = pack_bf16x2(e2, e3);
      pa0.wd[2] = pack_bf16x2(e4, e5); pa0.wd[3] = pack_bf16x2(e6, e7);
    }
    {
      const float e0 = exp2f(S[1][0][0]), e1 = exp2f(S[1][0][1]);
      const float e2 = exp2f(S[1][0][2]), e3 = exp2f(S[1][0][3]);
      const float e4 = exp2f(S[1][1][0]), e5 = exp2f(S[1][1][1]);
      const float e6 = exp2f(S[1][1][2]), e7 = exp2f(S[1][1][3]);
      lpart1 += ((e0 + e1) + (e2 + e3)) + ((e4 + e5) + (e6 + e7));
      pa1.wd[0] = pack_bf16x2(e0, e1); pa1.wd[1] = pack_bf16x2(e2, e3);
      pa1.wd[2] = pack_bf16x2(e4, e5); pa1.wd[3] = pack_bf16x2(e6, e7);
    }

    // ---- GEMM2 (swapped): O^T[q = 4lg+r][c = 16mt+l15] += P . kern ----
    oaccT[0][0] = __builtin_amdgcn_mfma_f32_16x16x32_bf16(pa0.v, kb0, oaccT[0][0], 0, 0, 0);
    oaccT[1][0] = __builtin_amdgcn_mfma_f32_16x16x32_bf16(pa1.v, kb0, oaccT[1][0], 0, 0, 0);
    oaccT[0][1] = __builtin_amdgcn_mfma_f32_16x16x32_bf16(pa0.v, kb1, oaccT[0][1], 0, 0, 0);
    oaccT[1][1] = __builtin_amdgcn_mfma_f32_16x16x32_bf16(pa1.v, kb1, oaccT[1][1], 0, 0, 0);
    oaccT[0][2] = __builtin_amdgcn_mfma_f32_16x16x32_bf16(pa0.v, kb2, oaccT[0][2], 0, 0, 0);
    oaccT[1][2] = __builtin_amdgcn_mfma_f32_16x16x32_bf16(pa1.v, kb2, oaccT[1][2], 0, 0, 0);
    oaccT[0][3] = __builtin_amdgcn_mfma_f32_16x16x32_bf16(pa0.v, kb3, oaccT[0][3], 0, 0, 0);
    oaccT[1][3] = __builtin_amdgcn_mfma_f32_16x16x32_bf16(pa1.v, kb3, oaccT[1][3], 0, 0, 0);
    cur ^= 1;
  }
#undef STAGE_KP

  // ---- reduce l partials over lane-groups, publish per p-group ----
  lpart0 += __shfl_xor(lpart0, 16); lpart0 += __shfl_xor(lpart0, 32);
  lpart1 += __shfl_xor(lpart1, 16); lpart1 += __shfl_xor(lpart1, 32);
  if (lg == 0) {
    mll[g][st * 32 + l15]      = lpart0;
    mll[g][st * 32 + 16 + l15] = lpart1;
  }
  __syncthreads();                                   // C1: loop LDS dead
  if (t < 64) {
    float L = 0.f;
#pragma unroll
    for (int k = 0; k < 8; ++k) L += mll[k][t];
    lw[(size_t)((h * 4 + b) * 64 + y) * 64 + t] = L;   // raw half-l
  }
  // combine O^T partials: 4 regions [c=64][q stride 68] f32 on dead staging LDS
  float* Rg = (float*)SM + (g >> 1) * 4352;
  if ((g & 1) == 0) {
#pragma unroll
    for (int s = 0; s < 2; ++s)
#pragma unroll
      for (int mt = 0; mt < 4; ++mt)
#pragma unroll
        for (int r = 0; r < 4; ++r)
          Rg[(16 * mt + l15) * 68 + st * 32 + s * 16 + 4 * lg + r] = oaccT[s][mt][r];
  }
  __syncthreads();                                   // C2
  if (g & 1) {
#pragma unroll
    for (int s = 0; s < 2; ++s)
#pragma unroll
      for (int mt = 0; mt < 4; ++mt)
#pragma unroll
        for (int r = 0; r < 4; ++r)
          Rg[(16 * mt + l15) * 68 + st * 32 + s * 16 + 4 * lg + r] += oaccT[s][mt][r];
  }
  __syncthreads();                                   // C3
  {
    const int c = t >> 4, q4 = (t & 15) * 4;
    const float* R0 = (const float*)SM;
    f32x4 v = *(const f32x4*)(R0 + c * 68 + q4);
    v += *(const f32x4*)(R0 + 4352 + c * 68 + q4);
    v += *(const f32x4*)(R0 + 8704 + c * 68 + q4);
    v += *(const f32x4*)(R0 + 13056 + c * 68 + q4);
    *(f32x4*)(dstO + (size_t)c * HW_ + y * 64 + q4) = v;   // raw partial sums
  }
}

// ---------------- reduce: out = (P0 + P1) / (l0 + l1), in place ----------------
__global__ __launch_bounds__(256, 8) void kca_reduce(float* __restrict__ out,
                                                     const float* __restrict__ po1,
                                                     const float* __restrict__ lw) {
  const size_t idx = ((size_t)blockIdx.x * 256 + threadIdx.x) * 4;  // element idx, q%4==0
  const int b = (int)(idx >> 18);
  const int y = (int)((idx >> 6) & 63);
  const int q = (int)(idx & 63);
  const size_t lidx = (size_t)(b * 64 + y) * 64 + q;
  const f32x4 a  = *(const f32x4*)(out + idx);
  const f32x4 p  = *(const f32x4*)(po1 + idx);
  const f32x4 l0 = *(const f32x4*)(lw + lidx);
  const f32x4 l1 = *(const f32x4*)(lw + 16384 + lidx);   // h-stride = 4*64*64 FLOATS
  f32x4 o;
#pragma unroll
  for (int j = 0; j < 4; ++j) o[j] = (a[j] + p[j]) * (1.0f / (l0[j] + l1[j]));
  *(f32x4*)(out + idx) = o;
}

extern "C" void kernel_launch(void* const* d_in, const int* in_sizes, int n_in,
                              void* d_out, int out_size, void* d_ws, size_t ws_size,
                              hipStream_t stream) {
  const float* fg = (const float*)d_in[0];
  float* out = (float*)d_out;
  char* ws = (char*)d_ws;
  char* Kp  = ws;                    // 2 MB  [b][p][c] bf16 (A-side kern)
  char* KB  = ws + (2u << 20);       // 2 MB  [b][tile][mt][lane][16B] (B-side kern)
  char* Gt  = ws + (4u << 20);       // 2 MB  [b][q][c] bf16 (pooled Q, log2e-scaled)
  float* PO1 = (float*)(ws + (6u << 20));   // 4 MB  half-1 partial O, out layout
  float* LW  = (float*)(ws + (10u << 20));  // 512 KB [h][b][y][64] l sums
  hipLaunchKernelGGL(kca_prep, dim3(256), dim3(1024), 0, stream, fg, Kp, KB, Gt);
  hipLaunchKernelGGL(kca_attn, dim3(512), dim3(1024), 0, stream, Kp, KB, Gt, out, PO1, LW);
  hipLaunchKernelGGL(kca_reduce, dim3(1024), dim3(256), 0, stream, out, PO1, LW);
}